// Round 1
// baseline (66.899 us; speedup 1.0000x reference)
//
#include <hip/hip_runtime.h>

#define Bb 128
#define Ww 128
#define Nn 512
#define ALPHA 0.2f

typedef __attribute__((ext_vector_type(8))) short short8;
typedef __attribute__((ext_vector_type(4))) float f32x4;

__device__ __forceinline__ unsigned f2bf_u(float f) {
  union { float f; unsigned u; } v; v.f = f;
  return (v.u + 0x7fffu + ((v.u >> 16) & 1u)) >> 16;  // RNE f32->bf16 (finite inputs)
}

// c[w] = sum_v a2[v] * W_fc[v,w];  c[128] = dot(b_fc, a2)
__global__ void prep_kernel(const float* __restrict__ Wfc, const float* __restrict__ bfc,
                            const float* __restrict__ attn, float* __restrict__ cvec) {
  const int w = threadIdx.x;  // 0..127
  float acc = 0.f;
#pragma unroll 8
  for (int v = 0; v < Ww; ++v) acc = fmaf(attn[Ww + v], Wfc[v * Ww + w], acc);
  cvec[w] = acc;
  __shared__ float red[Ww];
  red[w] = bfc[w] * attn[Ww + w];
  __syncthreads();
  if (w == 0) {
    float s = 0.f;
    for (int i = 0; i < Ww; ++i) s += red[i];
    cvec[Ww] = s;
  }
}

// Per block: batch b, 128 output rows (i). 4 waves, each 32 rows x 128 cols(w).
__launch_bounds__(256, 2)
__global__ void attn_main(const float* __restrict__ x, const float* __restrict__ attn,
                          const float* __restrict__ cvec, float* __restrict__ out) {
  const int b  = blockIdx.y;
  const int i0 = blockIdx.x * 128;
  const int t  = threadIdx.x;
  const int wv   = t >> 6;
  const int lane = t & 63;
  const int wl   = lane & 15;   // fragment "lane&15" index
  const int lg   = lane >> 4;   // 0..3

  const float* xb = x + (size_t)b * (Ww * Nn);

  __shared__ float  s1s[Nn];
  __shared__ float  s2s[Nn];
  __shared__ ushort tile[8][128][8];  // [j-group][w][8 j's] bf16, 16 KiB
  __shared__ float  lred[4][32];
  __shared__ float  redmax[4];

  // ---- prepass: s1[n], s2[n] for this batch; s2max ----
  {
    float a1x = 0.f, a1y = 0.f, a2x = 0.f, a2y = 0.f;
    const float c0 = cvec[Ww];
#pragma unroll 4
    for (int w = 0; w < Ww; ++w) {
      const float2 xv = *reinterpret_cast<const float2*>(xb + w * Nn + 2 * t);
      const float aw = attn[w];
      const float cw = cvec[w];
      a1x = fmaf(xv.x, aw, a1x); a1y = fmaf(xv.y, aw, a1y);
      a2x = fmaf(xv.x, cw, a2x); a2y = fmaf(xv.y, cw, a2y);
    }
    s1s[2 * t]     = a1x;
    s1s[2 * t + 1] = a1y;
    const float s2x = a2x + c0, s2y = a2y + c0;
    s2s[2 * t]     = s2x;
    s2s[2 * t + 1] = s2y;
    float m = fmaxf(s2x, s2y);
#pragma unroll
    for (int off = 1; off < 64; off <<= 1) m = fmaxf(m, __shfl_xor(m, off));
    if (lane == 0) redmax[wv] = m;
  }
  __syncthreads();
  const float s2maxb = fmaxf(fmaxf(redmax[0], redmax[1]), fmaxf(redmax[2], redmax[3]));

  // per-lane row constants (A-fragment rows: wv*32 + 16a + wl)
  float s1i[2], mi[2];
#pragma unroll
  for (int a = 0; a < 2; ++a) {
    const int r = wv * 32 + 16 * a + wl;
    const float s1v = s1s[i0 + r];
    s1i[a] = s1v;
    const float tt = s1v + s2maxb;
    mi[a] = fmaxf(tt, ALPHA * tt);  // lrelu is monotone -> row max
  }

  f32x4 acc[2][8];
#pragma unroll
  for (int a = 0; a < 2; ++a)
#pragma unroll
    for (int f = 0; f < 8; ++f) acc[a][f] = (f32x4){0.f, 0.f, 0.f, 0.f};
  float lsum0 = 0.f, lsum1 = 0.f;

  for (int r = 0; r < 8; ++r) {
    const int j0 = r * 64;
    __syncthreads();  // previous round's tile reads done
    // stage x[b][:][j0..j0+63] as bf16 into [jg][w][8]
#pragma unroll
    for (int k = 0; k < 4; ++k) {
      const int u = t + 256 * k;
      const int w = u & 127, jg = u >> 7;
      const float4* src = reinterpret_cast<const float4*>(xb + w * Nn + j0 + jg * 8);
      const float4 lo = src[0], hi = src[1];
      uint4 pk;
      pk.x = f2bf_u(lo.x) | (f2bf_u(lo.y) << 16);
      pk.y = f2bf_u(lo.z) | (f2bf_u(lo.w) << 16);
      pk.z = f2bf_u(hi.x) | (f2bf_u(hi.y) << 16);
      pk.w = f2bf_u(hi.z) | (f2bf_u(hi.w) << 16);
      *reinterpret_cast<uint4*>(&tile[jg][w][0]) = pk;
    }
    __syncthreads();

#pragma unroll
    for (int jj = 0; jj < 2; ++jj) {
      const int jb = j0 + jj * 32 + 8 * lg;  // this lane's 8 consecutive j's
      float sv[8];
      *reinterpret_cast<float4*>(&sv[0]) = *reinterpret_cast<const float4*>(&s2s[jb]);
      *reinterpret_cast<float4*>(&sv[4]) = *reinterpret_cast<const float4*>(&s2s[jb + 4]);
      short8 af0, af1;
#pragma unroll
      for (int e = 0; e < 8; ++e) {
        const float t0 = s1i[0] + sv[e];
        const float l0 = fmaxf(t0, ALPHA * t0);
        const float p0 = __expf(l0 - mi[0]);
        lsum0 += p0;
        af0[e] = (short)f2bf_u(p0);
        const float t1 = s1i[1] + sv[e];
        const float l1 = fmaxf(t1, ALPHA * t1);
        const float p1 = __expf(l1 - mi[1]);
        lsum1 += p1;
        af1[e] = (short)f2bf_u(p1);
      }
#pragma unroll
      for (int f = 0; f < 8; ++f) {
        const short8 bf = *reinterpret_cast<const short8*>(&tile[jj * 4 + lg][16 * f + wl][0]);
        acc[0][f] = __builtin_amdgcn_mfma_f32_16x16x32_bf16(af0, bf, acc[0][f], 0, 0, 0);
        acc[1][f] = __builtin_amdgcn_mfma_f32_16x16x32_bf16(af1, bf, acc[1][f], 0, 0, 0);
      }
    }
  }

  // reduce softmax denominators across the 4 k-groups holding each row
  lsum0 += __shfl_xor(lsum0, 16); lsum0 += __shfl_xor(lsum0, 32);
  lsum1 += __shfl_xor(lsum1, 16); lsum1 += __shfl_xor(lsum1, 32);
  if (lg == 0) { lred[wv][wl] = lsum0; lred[wv][16 + wl] = lsum1; }
  __syncthreads();

  float* outb = out + (size_t)b * (Ww * Nn);
#pragma unroll
  for (int a = 0; a < 2; ++a) {
    float invl[4];
#pragma unroll
    for (int q = 0; q < 4; ++q) invl[q] = 1.0f / lred[wv][16 * a + lg * 4 + q];
    const int ibase = i0 + wv * 32 + 16 * a + lg * 4;
#pragma unroll
    for (int f = 0; f < 8; ++f) {
      float4 o;
      o.x = 1.f / (1.f + __expf(-(acc[a][f][0] * invl[0])));
      o.y = 1.f / (1.f + __expf(-(acc[a][f][1] * invl[1])));
      o.z = 1.f / (1.f + __expf(-(acc[a][f][2] * invl[2])));
      o.w = 1.f / (1.f + __expf(-(acc[a][f][3] * invl[3])));
      *reinterpret_cast<float4*>(outb + (16 * f + wl) * Nn + ibase) = o;
    }
  }
}

extern "C" void kernel_launch(void* const* d_in, const int* in_sizes, int n_in,
                              void* d_out, int out_size, void* d_ws, size_t ws_size,
                              hipStream_t stream) {
  const float* x    = (const float*)d_in[0];  // (128,128,512)
  const float* Wfc  = (const float*)d_in[1];  // (128,128)
  const float* bfc  = (const float*)d_in[2];  // (128,)
  const float* attn = (const float*)d_in[3];  // (256,1)
  float* out  = (float*)d_out;                // (128,128,512)
  float* cvec = (float*)d_ws;                 // 129 floats

  prep_kernel<<<1, 128, 0, stream>>>(Wfc, bfc, attn, cvec);
  attn_main<<<dim3(4, Bb), 256, 0, stream>>>(x, attn, cvec, out);
}

// Round 2
// 42.999 us; speedup vs baseline: 1.5558x; 1.5558x over previous
//
#include <hip/hip_runtime.h>

#define Bb 128
#define Ww 128
#define Nn 512
#define ALPHA 0.2f

typedef __attribute__((ext_vector_type(8))) short short8;
typedef __attribute__((ext_vector_type(4))) float f32x4;

__device__ __forceinline__ unsigned f2bf_u(float f) {
  union { float f; unsigned u; } v; v.f = f;
  return (v.u + 0x7fffu + ((v.u >> 16) & 1u)) >> 16;  // RNE f32->bf16 (finite inputs)
}

__device__ __forceinline__ void gld_lds16(const void* g, void* l) {
  auto gp = reinterpret_cast<const __attribute__((address_space(1))) unsigned int*>(
      reinterpret_cast<uintptr_t>(g));
  auto lp = reinterpret_cast<__attribute__((address_space(3))) unsigned int*>(
      reinterpret_cast<uintptr_t>(l));
  __builtin_amdgcn_global_load_lds(gp, lp, 16, 0, 0);
}

// c[w] = sum_v a2[v] * W_fc[v,w];  c[128] = dot(b_fc, a2)
__global__ void prep_kernel(const float* __restrict__ Wfc, const float* __restrict__ bfc,
                            const float* __restrict__ attn, float* __restrict__ cvec) {
  const int w = threadIdx.x;  // 0..127
  float acc = 0.f;
#pragma unroll 8
  for (int v = 0; v < Ww; ++v) acc = fmaf(attn[Ww + v], Wfc[v * Ww + w], acc);
  cvec[w] = acc;
  __shared__ float red[Ww];
  red[w] = bfc[w] * attn[Ww + w];
  __syncthreads();
  if (w == 0) {
    float s = 0.f;
    for (int i = 0; i < Ww; ++i) s += red[i];
    cvec[Ww] = s;
  }
}

// Phase 1: per block (b, 128-n slab): read x once coalesced, compute s1/s2,
// emit bf16 x packed as xbf[b][jg=n>>3][w][n&7] (PV-staging-ready layout).
__launch_bounds__(256, 2)
__global__ void pack_kernel(const float* __restrict__ x, const float* __restrict__ attn,
                            const float* __restrict__ cvec, ushort* __restrict__ xbf,
                            float* __restrict__ s1g, float* __restrict__ s2g) {
  const int bid = blockIdx.x;
  const int b = bid >> 2, nc = bid & 3;
  const int n0 = nc * 128;
  const int t = threadIdx.x;
  const float* xb = x + (size_t)b * (Ww * Nn);

  __shared__ ushort tile[16][129][8];   // [jg_local][w(+pad)][8], 33 KB
  __shared__ float  sred[8][32][8];     // [w-group][q][s1x4|s2x4], 8 KB

  const int w0 = t >> 5;   // 0..7
  const int q  = t & 31;   // float4 index in row
  float s1p[4] = {0.f, 0.f, 0.f, 0.f};
  float s2p[4] = {0.f, 0.f, 0.f, 0.f};
#pragma unroll
  for (int k = 0; k < 16; ++k) {
    const int w = w0 + 8 * k;
    const float4 xv = *reinterpret_cast<const float4*>(xb + w * Nn + n0 + 4 * q);
    const float aw = attn[w];
    const float cw = cvec[w];
    s1p[0] = fmaf(xv.x, aw, s1p[0]); s1p[1] = fmaf(xv.y, aw, s1p[1]);
    s1p[2] = fmaf(xv.z, aw, s1p[2]); s1p[3] = fmaf(xv.w, aw, s1p[3]);
    s2p[0] = fmaf(xv.x, cw, s2p[0]); s2p[1] = fmaf(xv.y, cw, s2p[1]);
    s2p[2] = fmaf(xv.z, cw, s2p[2]); s2p[3] = fmaf(xv.w, cw, s2p[3]);
    uint2 pk;
    pk.x = f2bf_u(xv.x) | (f2bf_u(xv.y) << 16);
    pk.y = f2bf_u(xv.z) | (f2bf_u(xv.w) << 16);
    *reinterpret_cast<uint2*>(&tile[q >> 1][w][(q & 1) * 4]) = pk;
  }
  *reinterpret_cast<float4*>(&sred[w0][q][0]) = make_float4(s1p[0], s1p[1], s1p[2], s1p[3]);
  *reinterpret_cast<float4*>(&sred[w0][q][4]) = make_float4(s2p[0], s2p[1], s2p[2], s2p[3]);
  __syncthreads();

  if (t < 128) {
    const int qq = t >> 2, c = t & 3;
    float a = 0.f, d = 0.f;
#pragma unroll
    for (int g = 0; g < 8; ++g) { a += sred[g][qq][c]; d += sred[g][qq][4 + c]; }
    s1g[b * Nn + n0 + t] = a;
    s2g[b * Nn + n0 + t] = d + cvec[Ww];
  }

#pragma unroll
  for (int k = 0; k < 8; ++k) {
    const int c2 = t + 256 * k;
    const int jg = c2 >> 7, w = c2 & 127;
    const uint4 v = *reinterpret_cast<const uint4*>(&tile[jg][w][0]);
    *reinterpret_cast<uint4*>(xbf + (((size_t)b * 64 + nc * 16 + jg) * 128 + w) * 8) = v;
  }
}

// Phase 2: per block: batch b, 64 output rows (i). 4 waves x 16 rows.
// XCD-grouped decode: 8 i-tiles of a batch land on one XCD -> xbf L2-resident.
__launch_bounds__(256, 4)
__global__ void attn_main2(const ushort* __restrict__ xbf, const float* __restrict__ s1g,
                           const float* __restrict__ s2g, float* __restrict__ out) {
  const int bid = blockIdx.x;            // 0..1023
  const int xcd = bid & 7, idx = bid >> 3;
  const int b = xcd * 16 + (idx >> 3);
  const int i0 = (idx & 7) * 64;
  const int t = threadIdx.x;
  const int wv = t >> 6, lane = t & 63;
  const int wl = lane & 15, lg = lane >> 4;

  __shared__ float  s2s[Nn];
  __shared__ ushort tile[8][128][8];     // 16 KB
  __shared__ float  lred[4][16];
  __shared__ float  redmax[4];

  {
    const float v0 = s2g[b * Nn + t];
    const float v1 = s2g[b * Nn + 256 + t];
    s2s[t] = v0; s2s[256 + t] = v1;
    float m = fmaxf(v0, v1);
#pragma unroll
    for (int off = 1; off < 64; off <<= 1) m = fmaxf(m, __shfl_xor(m, off));
    if (lane == 0) redmax[wv] = m;
  }
  const float s1v = s1g[b * Nn + i0 + wv * 16 + wl];  // this lane's row
  __syncthreads();
  const float s2maxb = fmaxf(fmaxf(redmax[0], redmax[1]), fmaxf(redmax[2], redmax[3]));
  const float tt = s1v + s2maxb;
  const float mi = fmaxf(tt, ALPHA * tt);  // lrelu monotone -> row max

  f32x4 acc[8];
#pragma unroll
  for (int f = 0; f < 8; ++f) acc[f] = (f32x4){0.f, 0.f, 0.f, 0.f};
  float lsum = 0.f;

  const ushort* xsrc = xbf + (size_t)b * 64 * 128 * 8;
  ushort* ltile = &tile[0][0][0];

  for (int r = 0; r < 8; ++r) {
    __syncthreads();  // previous round's tile reads done
    const ushort* src = xsrc + (size_t)r * 8 * 128 * 8;
#pragma unroll
    for (int k = 0; k < 4; ++k) {
      const int off = t + 256 * k;
      gld_lds16(src + off * 8, ltile + off * 8);
    }
    __syncthreads();  // compiler drains vmcnt before barrier

    const int j0 = r * 64;
#pragma unroll
    for (int jj = 0; jj < 2; ++jj) {
      const int jb = j0 + jj * 32 + 8 * lg;  // this lane's 8 consecutive j's
      float sv[8];
      *reinterpret_cast<float4*>(&sv[0]) = *reinterpret_cast<const float4*>(&s2s[jb]);
      *reinterpret_cast<float4*>(&sv[4]) = *reinterpret_cast<const float4*>(&s2s[jb + 4]);
      short8 af;
#pragma unroll
      for (int e = 0; e < 8; ++e) {
        const float t0 = s1v + sv[e];
        const float l0 = fmaxf(t0, ALPHA * t0);
        const float p0 = __expf(l0 - mi);
        lsum += p0;
        af[e] = (short)f2bf_u(p0);
      }
#pragma unroll
      for (int f = 0; f < 8; ++f) {
        const short8 bfr = *reinterpret_cast<const short8*>(&tile[jj * 4 + lg][16 * f + wl][0]);
        acc[f] = __builtin_amdgcn_mfma_f32_16x16x32_bf16(af, bfr, acc[f], 0, 0, 0);
      }
    }
  }

  lsum += __shfl_xor(lsum, 16);
  lsum += __shfl_xor(lsum, 32);
  if (lg == 0) lred[wv][wl] = lsum;
  __syncthreads();

  float invl[4];
#pragma unroll
  for (int qq = 0; qq < 4; ++qq) invl[qq] = 1.0f / lred[wv][lg * 4 + qq];
  const int ibase = i0 + wv * 16 + lg * 4;
  float* outb = out + (size_t)b * (Ww * Nn);
#pragma unroll
  for (int f = 0; f < 8; ++f) {
    float4 o;
    o.x = 1.f / (1.f + __expf(-(acc[f][0] * invl[0])));
    o.y = 1.f / (1.f + __expf(-(acc[f][1] * invl[1])));
    o.z = 1.f / (1.f + __expf(-(acc[f][2] * invl[2])));
    o.w = 1.f / (1.f + __expf(-(acc[f][3] * invl[3])));
    *reinterpret_cast<float4*>(outb + (16 * f + wl) * Nn + ibase) = o;
  }
}

// ---------------- fallback (round-1 kernel, needs only 516 B of ws) ----------------
__launch_bounds__(256, 2)
__global__ void attn_main(const float* __restrict__ x, const float* __restrict__ attn,
                          const float* __restrict__ cvec, float* __restrict__ out) {
  const int b  = blockIdx.y;
  const int i0 = blockIdx.x * 128;
  const int t  = threadIdx.x;
  const int wv   = t >> 6;
  const int lane = t & 63;
  const int wl   = lane & 15;
  const int lg   = lane >> 4;
  const float* xb = x + (size_t)b * (Ww * Nn);

  __shared__ float  s1s[Nn];
  __shared__ float  s2s[Nn];
  __shared__ ushort tile[8][128][8];
  __shared__ float  lred[4][32];
  __shared__ float  redmax[4];

  {
    float a1x = 0.f, a1y = 0.f, a2x = 0.f, a2y = 0.f;
    const float c0 = cvec[Ww];
#pragma unroll 4
    for (int w = 0; w < Ww; ++w) {
      const float2 xv = *reinterpret_cast<const float2*>(xb + w * Nn + 2 * t);
      const float aw = attn[w];
      const float cw = cvec[w];
      a1x = fmaf(xv.x, aw, a1x); a1y = fmaf(xv.y, aw, a1y);
      a2x = fmaf(xv.x, cw, a2x); a2y = fmaf(xv.y, cw, a2y);
    }
    s1s[2 * t] = a1x; s1s[2 * t + 1] = a1y;
    const float s2x = a2x + c0, s2y = a2y + c0;
    s2s[2 * t] = s2x; s2s[2 * t + 1] = s2y;
    float m = fmaxf(s2x, s2y);
#pragma unroll
    for (int off = 1; off < 64; off <<= 1) m = fmaxf(m, __shfl_xor(m, off));
    if (lane == 0) redmax[wv] = m;
  }
  __syncthreads();
  const float s2maxb = fmaxf(fmaxf(redmax[0], redmax[1]), fmaxf(redmax[2], redmax[3]));

  float s1i[2], mi[2];
#pragma unroll
  for (int a = 0; a < 2; ++a) {
    const int r = wv * 32 + 16 * a + wl;
    const float s1v = s1s[i0 + r];
    s1i[a] = s1v;
    const float tt = s1v + s2maxb;
    mi[a] = fmaxf(tt, ALPHA * tt);
  }

  f32x4 acc[2][8];
#pragma unroll
  for (int a = 0; a < 2; ++a)
#pragma unroll
    for (int f = 0; f < 8; ++f) acc[a][f] = (f32x4){0.f, 0.f, 0.f, 0.f};
  float lsum0 = 0.f, lsum1 = 0.f;

  for (int r = 0; r < 8; ++r) {
    const int j0 = r * 64;
    __syncthreads();
#pragma unroll
    for (int k = 0; k < 4; ++k) {
      const int u = t + 256 * k;
      const int w = u & 127, jg = u >> 7;
      const float4* src = reinterpret_cast<const float4*>(xb + w * Nn + j0 + jg * 8);
      const float4 lo = src[0], hi = src[1];
      uint4 pk;
      pk.x = f2bf_u(lo.x) | (f2bf_u(lo.y) << 16);
      pk.y = f2bf_u(lo.z) | (f2bf_u(lo.w) << 16);
      pk.z = f2bf_u(hi.x) | (f2bf_u(hi.y) << 16);
      pk.w = f2bf_u(hi.z) | (f2bf_u(hi.w) << 16);
      *reinterpret_cast<uint4*>(&tile[jg][w][0]) = pk;
    }
    __syncthreads();

#pragma unroll
    for (int jj = 0; jj < 2; ++jj) {
      const int jb = j0 + jj * 32 + 8 * lg;
      float sv[8];
      *reinterpret_cast<float4*>(&sv[0]) = *reinterpret_cast<const float4*>(&s2s[jb]);
      *reinterpret_cast<float4*>(&sv[4]) = *reinterpret_cast<const float4*>(&s2s[jb + 4]);
      short8 af0, af1;
#pragma unroll
      for (int e = 0; e < 8; ++e) {
        const float t0 = s1i[0] + sv[e];
        const float l0 = fmaxf(t0, ALPHA * t0);
        const float p0 = __expf(l0 - mi[0]);
        lsum0 += p0;
        af0[e] = (short)f2bf_u(p0);
        const float t1 = s1i[1] + sv[e];
        const float l1 = fmaxf(t1, ALPHA * t1);
        const float p1 = __expf(l1 - mi[1]);
        lsum1 += p1;
        af1[e] = (short)f2bf_u(p1);
      }
#pragma unroll
      for (int f = 0; f < 8; ++f) {
        const short8 bfr = *reinterpret_cast<const short8*>(&tile[jj * 4 + lg][16 * f + wl][0]);
        acc[0][f] = __builtin_amdgcn_mfma_f32_16x16x32_bf16(af0, bfr, acc[0][f], 0, 0, 0);
        acc[1][f] = __builtin_amdgcn_mfma_f32_16x16x32_bf16(af1, bfr, acc[1][f], 0, 0, 0);
      }
    }
  }

  lsum0 += __shfl_xor(lsum0, 16); lsum0 += __shfl_xor(lsum0, 32);
  lsum1 += __shfl_xor(lsum1, 16); lsum1 += __shfl_xor(lsum1, 32);
  if (lg == 0) { lred[wv][wl] = lsum0; lred[wv][16 + wl] = lsum1; }
  __syncthreads();

  float* outb = out + (size_t)b * (Ww * Nn);
#pragma unroll
  for (int a = 0; a < 2; ++a) {
    float invl[4];
#pragma unroll
    for (int qq = 0; qq < 4; ++qq) invl[qq] = 1.0f / lred[wv][16 * a + lg * 4 + qq];
    const int ibase = i0 + wv * 32 + 16 * a + lg * 4;
#pragma unroll
    for (int f = 0; f < 8; ++f) {
      float4 o;
      o.x = 1.f / (1.f + __expf(-(acc[a][f][0] * invl[0])));
      o.y = 1.f / (1.f + __expf(-(acc[a][f][1] * invl[1])));
      o.z = 1.f / (1.f + __expf(-(acc[a][f][2] * invl[2])));
      o.w = 1.f / (1.f + __expf(-(acc[a][f][3] * invl[3])));
      *reinterpret_cast<float4*>(outb + (16 * f + wl) * Nn + ibase) = o;
    }
  }
}

extern "C" void kernel_launch(void* const* d_in, const int* in_sizes, int n_in,
                              void* d_out, int out_size, void* d_ws, size_t ws_size,
                              hipStream_t stream) {
  const float* x    = (const float*)d_in[0];  // (128,128,512)
  const float* Wfc  = (const float*)d_in[1];  // (128,128)
  const float* bfc  = (const float*)d_in[2];  // (128,)
  const float* attn = (const float*)d_in[3];  // (256,1)
  float* out = (float*)d_out;                 // (128,128,512)

  char* ws = (char*)d_ws;
  float*  cvec = (float*)ws;                    // 516 B (pad to 1024)
  float*  s1g  = (float*)(ws + 1024);           // 256 KB
  float*  s2g  = (float*)(ws + 1024 + 262144);  // 256 KB
  ushort* xbf  = (ushort*)(ws + 1024 + 2 * 262144);  // 16 MB
  const size_t NEED = 1024 + 2 * 262144 + (size_t)Bb * 64 * 128 * 8 * 2;

  prep_kernel<<<1, 128, 0, stream>>>(Wfc, bfc, attn, cvec);
  if (ws_size >= NEED) {
    pack_kernel<<<512, 256, 0, stream>>>(x, attn, cvec, xbf, s1g, s2g);
    attn_main2<<<1024, 256, 0, stream>>>(xbf, s1g, s2g, out);
  } else {
    attn_main<<<dim3(4, Bb), 256, 0, stream>>>(x, attn, cvec, out);
  }
}

// Round 3
// 33.883 us; speedup vs baseline: 1.9744x; 1.2691x over previous
//
#include <hip/hip_runtime.h>

#define Bb 128
#define Ww 128
#define Nn 512
#define ALPHA 0.2f

typedef __attribute__((ext_vector_type(8))) short short8;
typedef __attribute__((ext_vector_type(4))) float f32x4;

__device__ __forceinline__ unsigned f2bf_u(float f) {
  union { float f; unsigned u; } v; v.f = f;
  return (v.u + 0x7fffu + ((v.u >> 16) & 1u)) >> 16;  // RNE f32->bf16 (finite inputs)
}

// ---- dynamic LDS layout (bytes) ----
#define TILE_OFF   0
#define TILE_BYTES (64 * 129 * 8 * 2)          // ushort tile[64][129][8] = 132096
#define SRED_OFF   (TILE_OFF + TILE_BYTES)     // float sred[512*8]       = 16384
#define S1S_OFF    (SRED_OFF + 16384)          // float s1s[512]          = 2048
#define S2S_OFF    (S1S_OFF + 2048)            // float s2s[512]          = 2048
#define CVS_OFF    (S2S_OFF + 2048)            // float cvs[129] (pad 528)
#define A1S_OFF    (CVS_OFF + 528)             // float a1s[128]          = 512
#define LRED_OFF   (A1S_OFF + 512)             // float lred[8][32]       = 1024
#define RMAX_OFF   (LRED_OFF + 1024)           // float rmax[8]           = 32
#define SMEM_BYTES (RMAX_OFF + 32)             // = 154672 < 160 KiB

// One block = (batch b, i-half). 512 threads = 8 waves; each wave 32 i-rows x 128 w.
// Blocks bid and bid+8 share batch b and (round-robin dispatch) the same XCD/L2.
__launch_bounds__(512, 2)
__global__ void attn_fused(const float* __restrict__ x, const float* __restrict__ Wfc,
                           const float* __restrict__ bfc, const float* __restrict__ attn,
                           float* __restrict__ out) {
  extern __shared__ char smem[];
  ushort* tile = (ushort*)(smem + TILE_OFF);
  float*  sred = (float*)(smem + SRED_OFF);
  float*  s1s  = (float*)(smem + S1S_OFF);
  float*  s2s  = (float*)(smem + S2S_OFF);
  float*  cvs  = (float*)(smem + CVS_OFF);
  float*  a1s  = (float*)(smem + A1S_OFF);
  float*  lred = (float*)(smem + LRED_OFF);
  float*  rmax = (float*)(smem + RMAX_OFF);

  const int bid = blockIdx.x;
  const int xcd = bid & 7, idx = bid >> 3;
  const int b  = xcd * 16 + (idx >> 1);
  const int i0 = (idx & 1) * 256;
  const int t  = threadIdx.x;
  const int wv = t >> 6, lane = t & 63;
  const int wl = lane & 15, lg = lane >> 4;
  const float* xb = x + (size_t)b * (Ww * Nn);

  // ---- P0: cvec partials (coalesced Wfc), a1 stash, c0 ----
  {
    const int wcol = t & 127, vq = t >> 7;  // 4 v-quarters x 128 w-cols
    float p = 0.f;
#pragma unroll 8
    for (int vi = 0; vi < 32; ++vi) {
      const int v = vq * 32 + vi;
      p = fmaf(attn[Ww + v], Wfc[v * Ww + wcol], p);
    }
    sred[t] = p;
    if (t < Ww) a1s[t] = attn[t];
    if (t < 64) {  // wave 0: c0 = dot(b_fc, a2)
      float c0p = fmaf(bfc[t], attn[Ww + t], bfc[t + 64] * attn[Ww + 64 + t]);
#pragma unroll
      for (int off = 32; off; off >>= 1) c0p += __shfl_xor(c0p, off);
      if (t == 0) cvs[Ww] = c0p;
    }
  }
  __syncthreads();
  if (t < Ww) cvs[t] = sred[t] + sred[t + 128] + sred[t + 256] + sred[t + 384];
  __syncthreads();

  // ---- P1: stream x[b] once; accumulate s1/s2 partials; write bf16 tile ----
  // Thread (w0=t>>6, q=t&63) owns n-slice [8q, 8q+8) for rows w = w0+8k.
  const int q = t & 63;
  float s1p[8] = {0, 0, 0, 0, 0, 0, 0, 0};
  float s2p[8] = {0, 0, 0, 0, 0, 0, 0, 0};
#pragma unroll
  for (int k = 0; k < 16; ++k) {
    const int w = wv + 8 * k;
    const float aw = a1s[w];
    const float cw = cvs[w];
    const float4 lo = *reinterpret_cast<const float4*>(xb + w * Nn + 8 * q);
    const float4 hi = *reinterpret_cast<const float4*>(xb + w * Nn + 8 * q + 4);
    s1p[0] = fmaf(lo.x, aw, s1p[0]); s1p[1] = fmaf(lo.y, aw, s1p[1]);
    s1p[2] = fmaf(lo.z, aw, s1p[2]); s1p[3] = fmaf(lo.w, aw, s1p[3]);
    s1p[4] = fmaf(hi.x, aw, s1p[4]); s1p[5] = fmaf(hi.y, aw, s1p[5]);
    s1p[6] = fmaf(hi.z, aw, s1p[6]); s1p[7] = fmaf(hi.w, aw, s1p[7]);
    s2p[0] = fmaf(lo.x, cw, s2p[0]); s2p[1] = fmaf(lo.y, cw, s2p[1]);
    s2p[2] = fmaf(lo.z, cw, s2p[2]); s2p[3] = fmaf(lo.w, cw, s2p[3]);
    s2p[4] = fmaf(hi.x, cw, s2p[4]); s2p[5] = fmaf(hi.y, cw, s2p[5]);
    s2p[6] = fmaf(hi.z, cw, s2p[6]); s2p[7] = fmaf(hi.w, cw, s2p[7]);
    uint4 pk;
    pk.x = f2bf_u(lo.x) | (f2bf_u(lo.y) << 16);
    pk.y = f2bf_u(lo.z) | (f2bf_u(lo.w) << 16);
    pk.z = f2bf_u(hi.x) | (f2bf_u(hi.y) << 16);
    pk.w = f2bf_u(hi.z) | (f2bf_u(hi.w) << 16);
    *reinterpret_cast<uint4*>(tile + ((size_t)q * 129 + w) * 8) = pk;  // conflict-free
  }

  // ---- P2: reduce s1/s2 across the 8 w-groups (two rounds through sred) ----
  {
    f32x4* sv = reinterpret_cast<f32x4*>(&sred[t * 8]);
    sv[0] = (f32x4){s1p[0], s1p[1], s1p[2], s1p[3]};
    sv[1] = (f32x4){s1p[4], s1p[5], s1p[6], s1p[7]};
  }
  __syncthreads();
  {
    const int qq = t >> 3, ee = t & 7;
    float a = 0.f;
#pragma unroll
    for (int g = 0; g < 8; ++g) a += sred[((g * 64) + qq) * 8 + ee];
    s1s[t] = a;
  }
  __syncthreads();
  {
    f32x4* sv = reinterpret_cast<f32x4*>(&sred[t * 8]);
    sv[0] = (f32x4){s2p[0], s2p[1], s2p[2], s2p[3]};
    sv[1] = (f32x4){s2p[4], s2p[5], s2p[6], s2p[7]};
  }
  __syncthreads();
  {
    const int qq = t >> 3, ee = t & 7;
    float d = 0.f;
#pragma unroll
    for (int g = 0; g < 8; ++g) d += sred[((g * 64) + qq) * 8 + ee];
    s2s[t] = d + cvs[Ww];
  }

  // ---- P3: s2max (own value -> wave reduce) ----
  {
    float m = s2s[t];
#pragma unroll
    for (int off = 1; off < 64; off <<= 1) m = fmaxf(m, __shfl_xor(m, off));
    if (lane == 0) rmax[wv] = m;
  }
  __syncthreads();
  float s2m = rmax[0];
#pragma unroll
  for (int g = 1; g < 8; ++g) s2m = fmaxf(s2m, rmax[g]);

  // per-lane row constants (rows i0 + wv*32 + 16a + wl)
  float s1i[2], mi[2];
#pragma unroll
  for (int a = 0; a < 2; ++a) {
    const float s1v = s1s[i0 + wv * 32 + 16 * a + wl];
    s1i[a] = s1v;
    const float tt = s1v + s2m;
    mi[a] = fmaxf(tt, ALPHA * tt);  // lrelu monotone -> row max
  }

  // ---- P4: barrier-free MFMA loop over all 512 j ----
  f32x4 acc[2][8];
#pragma unroll
  for (int a = 0; a < 2; ++a)
#pragma unroll
    for (int f = 0; f < 8; ++f) acc[a][f] = (f32x4){0.f, 0.f, 0.f, 0.f};
  float lsum0 = 0.f, lsum1 = 0.f;

  for (int jj = 0; jj < 16; ++jj) {
    const int jb = jj * 32 + 8 * lg;  // this lane's 8 consecutive j's
    float sv[8];
    *reinterpret_cast<float4*>(&sv[0]) = *reinterpret_cast<const float4*>(&s2s[jb]);
    *reinterpret_cast<float4*>(&sv[4]) = *reinterpret_cast<const float4*>(&s2s[jb + 4]);
    short8 af0, af1;
#pragma unroll
    for (int e = 0; e < 8; ++e) {
      const float t0 = s1i[0] + sv[e];
      const float l0 = fmaxf(t0, ALPHA * t0);
      const float p0 = __expf(l0 - mi[0]);
      lsum0 += p0;
      af0[e] = (short)f2bf_u(p0);
      const float t1 = s1i[1] + sv[e];
      const float l1 = fmaxf(t1, ALPHA * t1);
      const float p1 = __expf(l1 - mi[1]);
      lsum1 += p1;
      af1[e] = (short)f2bf_u(p1);
    }
    const int jg = jj * 4 + lg;
#pragma unroll
    for (int f = 0; f < 8; ++f) {
      const short8 bfr = *reinterpret_cast<const short8*>(tile + ((size_t)jg * 129 + 16 * f + wl) * 8);
      acc[0][f] = __builtin_amdgcn_mfma_f32_16x16x32_bf16(af0, bfr, acc[0][f], 0, 0, 0);
      acc[1][f] = __builtin_amdgcn_mfma_f32_16x16x32_bf16(af1, bfr, acc[1][f], 0, 0, 0);
    }
  }

  // ---- P5: softmax denominators ----
  lsum0 += __shfl_xor(lsum0, 16); lsum0 += __shfl_xor(lsum0, 32);
  lsum1 += __shfl_xor(lsum1, 16); lsum1 += __shfl_xor(lsum1, 32);
  if (lg == 0) { lred[wv * 32 + wl] = lsum0; lred[wv * 32 + 16 + wl] = lsum1; }
  __syncthreads();

  // ---- P6: epilogue ----
  float* outb = out + (size_t)b * (Ww * Nn);
#pragma unroll
  for (int a = 0; a < 2; ++a) {
    float invl[4];
#pragma unroll
    for (int qq = 0; qq < 4; ++qq) invl[qq] = 1.0f / lred[wv * 32 + 16 * a + lg * 4 + qq];
    const int ibase = i0 + wv * 32 + 16 * a + lg * 4;
#pragma unroll
    for (int f = 0; f < 8; ++f) {
      float4 o;
      o.x = 1.f / (1.f + __expf(-(acc[a][f][0] * invl[0])));
      o.y = 1.f / (1.f + __expf(-(acc[a][f][1] * invl[1])));
      o.z = 1.f / (1.f + __expf(-(acc[a][f][2] * invl[2])));
      o.w = 1.f / (1.f + __expf(-(acc[a][f][3] * invl[3])));
      *reinterpret_cast<float4*>(outb + (16 * f + wl) * Nn + ibase) = o;
    }
  }
}

// ---------------- fallback path (round-1, proven): prep + attn_main ----------------
__global__ void prep_kernel(const float* __restrict__ Wfc, const float* __restrict__ bfc,
                            const float* __restrict__ attn, float* __restrict__ cvec) {
  const int w = threadIdx.x;
  float acc = 0.f;
#pragma unroll 8
  for (int v = 0; v < Ww; ++v) acc = fmaf(attn[Ww + v], Wfc[v * Ww + w], acc);
  cvec[w] = acc;
  __shared__ float red[Ww];
  red[w] = bfc[w] * attn[Ww + w];
  __syncthreads();
  if (w == 0) {
    float s = 0.f;
    for (int i = 0; i < Ww; ++i) s += red[i];
    cvec[Ww] = s;
  }
}

__launch_bounds__(256, 2)
__global__ void attn_main(const float* __restrict__ x, const float* __restrict__ attn,
                          const float* __restrict__ cvec, float* __restrict__ out) {
  const int b  = blockIdx.y;
  const int i0 = blockIdx.x * 128;
  const int t  = threadIdx.x;
  const int wv   = t >> 6;
  const int lane = t & 63;
  const int wl   = lane & 15;
  const int lg   = lane >> 4;
  const float* xb = x + (size_t)b * (Ww * Nn);

  __shared__ float  s1s[Nn];
  __shared__ float  s2s[Nn];
  __shared__ ushort tile[8][128][8];
  __shared__ float  lred[4][32];
  __shared__ float  redmax[4];

  {
    float a1x = 0.f, a1y = 0.f, a2x = 0.f, a2y = 0.f;
    const float c0 = cvec[Ww];
#pragma unroll 4
    for (int w = 0; w < Ww; ++w) {
      const float2 xv = *reinterpret_cast<const float2*>(xb + w * Nn + 2 * t);
      const float aw = attn[w];
      const float cw = cvec[w];
      a1x = fmaf(xv.x, aw, a1x); a1y = fmaf(xv.y, aw, a1y);
      a2x = fmaf(xv.x, cw, a2x); a2y = fmaf(xv.y, cw, a2y);
    }
    s1s[2 * t] = a1x; s1s[2 * t + 1] = a1y;
    const float s2x = a2x + c0, s2y = a2y + c0;
    s2s[2 * t] = s2x; s2s[2 * t + 1] = s2y;
    float m = fmaxf(s2x, s2y);
#pragma unroll
    for (int off = 1; off < 64; off <<= 1) m = fmaxf(m, __shfl_xor(m, off));
    if (lane == 0) redmax[wv] = m;
  }
  __syncthreads();
  const float s2maxb = fmaxf(fmaxf(redmax[0], redmax[1]), fmaxf(redmax[2], redmax[3]));

  float s1i[2], mi[2];
#pragma unroll
  for (int a = 0; a < 2; ++a) {
    const int r = wv * 32 + 16 * a + wl;
    const float s1v = s1s[i0 + r];
    s1i[a] = s1v;
    const float tt = s1v + s2maxb;
    mi[a] = fmaxf(tt, ALPHA * tt);
  }

  f32x4 acc[2][8];
#pragma unroll
  for (int a = 0; a < 2; ++a)
#pragma unroll
    for (int f = 0; f < 8; ++f) acc[a][f] = (f32x4){0.f, 0.f, 0.f, 0.f};
  float lsum0 = 0.f, lsum1 = 0.f;

  for (int r = 0; r < 8; ++r) {
    const int j0 = r * 64;
    __syncthreads();
#pragma unroll
    for (int k = 0; k < 4; ++k) {
      const int u = t + 256 * k;
      const int w = u & 127, jg = u >> 7;
      const float4* src = reinterpret_cast<const float4*>(xb + w * Nn + j0 + jg * 8);
      const float4 lo = src[0], hi = src[1];
      uint4 pk;
      pk.x = f2bf_u(lo.x) | (f2bf_u(lo.y) << 16);
      pk.y = f2bf_u(lo.z) | (f2bf_u(lo.w) << 16);
      pk.z = f2bf_u(hi.x) | (f2bf_u(hi.y) << 16);
      pk.w = f2bf_u(hi.z) | (f2bf_u(hi.w) << 16);
      *reinterpret_cast<uint4*>(&tile[jg][w][0]) = pk;
    }
    __syncthreads();

#pragma unroll
    for (int jj = 0; jj < 2; ++jj) {
      const int jb = j0 + jj * 32 + 8 * lg;
      float sv[8];
      *reinterpret_cast<float4*>(&sv[0]) = *reinterpret_cast<const float4*>(&s2s[jb]);
      *reinterpret_cast<float4*>(&sv[4]) = *reinterpret_cast<const float4*>(&s2s[jb + 4]);
      short8 af0, af1;
#pragma unroll
      for (int e = 0; e < 8; ++e) {
        const float t0 = s1i[0] + sv[e];
        const float l0 = fmaxf(t0, ALPHA * t0);
        const float p0 = __expf(l0 - mi[0]);
        lsum0 += p0;
        af0[e] = (short)f2bf_u(p0);
        const float t1 = s1i[1] + sv[e];
        const float l1 = fmaxf(t1, ALPHA * t1);
        const float p1 = __expf(l1 - mi[1]);
        lsum1 += p1;
        af1[e] = (short)f2bf_u(p1);
      }
#pragma unroll
      for (int f = 0; f < 8; ++f) {
        const short8 bfr = *reinterpret_cast<const short8*>(&tile[jj * 4 + lg][16 * f + wl][0]);
        acc[0][f] = __builtin_amdgcn_mfma_f32_16x16x32_bf16(af0, bfr, acc[0][f], 0, 0, 0);
        acc[1][f] = __builtin_amdgcn_mfma_f32_16x16x32_bf16(af1, bfr, acc[1][f], 0, 0, 0);
      }
    }
  }

  lsum0 += __shfl_xor(lsum0, 16); lsum0 += __shfl_xor(lsum0, 32);
  lsum1 += __shfl_xor(lsum1, 16); lsum1 += __shfl_xor(lsum1, 32);
  if (lg == 0) { lred[wv][wl] = lsum0; lred[wv][16 + wl] = lsum1; }
  __syncthreads();

  float* outb = out + (size_t)b * (Ww * Nn);
#pragma unroll
  for (int a = 0; a < 2; ++a) {
    float invl[4];
#pragma unroll
    for (int qq = 0; qq < 4; ++qq) invl[qq] = 1.0f / lred[wv][16 * a + lg * 4 + qq];
    const int ibase = i0 + wv * 32 + 16 * a + lg * 4;
#pragma unroll
    for (int f = 0; f < 8; ++f) {
      float4 o;
      o.x = 1.f / (1.f + __expf(-(acc[a][f][0] * invl[0])));
      o.y = 1.f / (1.f + __expf(-(acc[a][f][1] * invl[1])));
      o.z = 1.f / (1.f + __expf(-(acc[a][f][2] * invl[2])));
      o.w = 1.f / (1.f + __expf(-(acc[a][f][3] * invl[3])));
      *reinterpret_cast<float4*>(outb + (16 * f + wl) * Nn + ibase) = o;
    }
  }
}

extern "C" void kernel_launch(void* const* d_in, const int* in_sizes, int n_in,
                              void* d_out, int out_size, void* d_ws, size_t ws_size,
                              hipStream_t stream) {
  const float* x    = (const float*)d_in[0];  // (128,128,512)
  const float* Wfc  = (const float*)d_in[1];  // (128,128)
  const float* bfc  = (const float*)d_in[2];  // (128,)
  const float* attn = (const float*)d_in[3];  // (256,1)
  float* out = (float*)d_out;                 // (128,128,512)

  hipError_t e = hipFuncSetAttribute(reinterpret_cast<const void*>(&attn_fused),
                                     hipFuncAttributeMaxDynamicSharedMemorySize,
                                     SMEM_BYTES);
  if (e == hipSuccess) {
    attn_fused<<<256, 512, SMEM_BYTES, stream>>>(x, Wfc, bfc, attn, out);
  } else {
    (void)hipGetLastError();  // clear sticky error, take the proven fallback
    float* cvec = (float*)d_ws;  // 129 floats
    prep_kernel<<<1, 128, 0, stream>>>(Wfc, bfc, attn, cvec);
    attn_main<<<dim3(4, Bb), 256, 0, stream>>>(x, attn, cvec, out);
  }
}